// Round 2
// baseline (871.343 us; speedup 1.0000x reference)
//
#include <hip/hip_runtime.h>
#include <hip/hip_bf16.h>

// Problem constants (fixed by reference)
constexpr int NN = 100000;   // nodes
constexpr int NE = 3200000;  // edges
constexpr int NF = 128;      // in feats
constexpr int NH = 128;      // hidden
constexpr int NC = 16;       // classes
constexpr int SCAN_CHUNK = 512;
constexpr int NB = (NN + SCAN_CHUNK - 1) / SCAN_CHUNK;  // 196 scan blocks

// ---------------- GEMM1: xw1 = x @ W1  [NN,128]x[128,128] ----------------
__global__ __launch_bounds__(256) void k_gemm1(const float* __restrict__ x,
                                               const float* __restrict__ W,
                                               float* __restrict__ y) {
    __shared__ float ws_[128 * 128];   // 64 KB: whole W1
    __shared__ float xs[8][128];       // 8 staged rows
    const int t = threadIdx.x;
    for (int i = t; i < 128 * 128; i += 256) ws_[i] = W[i];

    const int rowg = t >> 5;          // 0..7 (row within sub-tile)
    const int cq   = (t & 31) * 4;    // 4 output cols via float4
    const int row0 = blockIdx.x * 32;

    for (int rs = 0; rs < 32; rs += 8) {
        __syncthreads();
        {   // stage 8 rows (1024 floats) as 256 float4s
            const int r  = t >> 5;
            const int c4 = (t & 31) * 4;
            const int row = row0 + rs + r;
            float4 val = (row < NN) ? *(const float4*)(x + row * 128 + c4)
                                    : make_float4(0.f, 0.f, 0.f, 0.f);
            *(float4*)(&xs[r][c4]) = val;
        }
        __syncthreads();
        float4 acc = make_float4(0.f, 0.f, 0.f, 0.f);
#pragma unroll
        for (int k = 0; k < 128; ++k) {
            const float xv = xs[rowg][k];
            const float4 wv = *(const float4*)(&ws_[k * 128 + cq]);
            acc.x = fmaf(xv, wv.x, acc.x);
            acc.y = fmaf(xv, wv.y, acc.y);
            acc.z = fmaf(xv, wv.z, acc.z);
            acc.w = fmaf(xv, wv.w, acc.w);
        }
        const int row = row0 + rs + rowg;
        if (row < NN) *(float4*)(y + row * 128 + cq) = acc;
    }
}

// ---------------- CSR build ----------------
__global__ __launch_bounds__(256) void k_hist(const int* __restrict__ row, int* __restrict__ cnt) {
    int i = blockIdx.x * 256 + threadIdx.x;
    if (i < NE) atomicAdd(&cnt[row[i]], 1);
}

__global__ __launch_bounds__(256) void k_scanA(const int* __restrict__ cnt, int* __restrict__ bsum) {
    __shared__ int sd[256];
    const int t = threadIdx.x;
    const int i0 = blockIdx.x * SCAN_CHUNK + t * 2;
    int s = 0;
    if (i0 < NN) s += cnt[i0];
    if (i0 + 1 < NN) s += cnt[i0 + 1];
    sd[t] = s;
    __syncthreads();
    for (int off = 128; off > 0; off >>= 1) {
        if (t < off) sd[t] += sd[t + off];
        __syncthreads();
    }
    if (t == 0) bsum[blockIdx.x] = sd[0];
}

__global__ __launch_bounds__(256) void k_scanB(int* __restrict__ bsum) {
    __shared__ int sd[256];
    const int t = threadIdx.x;
    const int v = (t < NB) ? bsum[t] : 0;
    sd[t] = v;
    __syncthreads();
    for (int off = 1; off < 256; off <<= 1) {
        int a = sd[t];
        int b = (t >= off) ? sd[t - off] : 0;
        __syncthreads();
        sd[t] = a + b;
        __syncthreads();
    }
    if (t < NB) bsum[t] = sd[t] - v;  // exclusive
}

__global__ __launch_bounds__(256) void k_scanC(const int* __restrict__ cnt,
                                               const int* __restrict__ bsum,
                                               int* __restrict__ row_start,
                                               int* __restrict__ cursor) {
    __shared__ int sd[256];
    const int t = threadIdx.x;
    const int i0 = blockIdx.x * SCAN_CHUNK + t * 2;
    const int c0 = (i0 < NN) ? cnt[i0] : 0;
    const int c1 = (i0 + 1 < NN) ? cnt[i0 + 1] : 0;
    const int s = c0 + c1;
    sd[t] = s;
    __syncthreads();
    for (int off = 1; off < 256; off <<= 1) {
        int a = sd[t];
        int b = (t >= off) ? sd[t - off] : 0;
        __syncthreads();
        sd[t] = a + b;
        __syncthreads();
    }
    const int excl = sd[t] - s + bsum[blockIdx.x];
    if (i0 < NN)     { row_start[i0] = excl;          cursor[i0] = excl; }
    if (i0 + 1 < NN) { row_start[i0 + 1] = excl + c0; cursor[i0 + 1] = excl + c0; }
    if (blockIdx.x == 0 && t == 0) row_start[NN] = NE;
}

__global__ __launch_bounds__(256) void k_scatter(const int* __restrict__ erow,
                                                 const int* __restrict__ ecol,
                                                 const float* __restrict__ eval_,
                                                 int* __restrict__ cursor,
                                                 int* __restrict__ csr_col,
                                                 float* __restrict__ csr_val) {
    int i = blockIdx.x * 256 + threadIdx.x;
    if (i < NE) {
        int r = erow[i];
        int p = atomicAdd(&cursor[r], 1);
        csr_col[p] = ecol[i];
        csr_val[p] = eval_[i];
    }
}

// ---------------- SpMM1 + bias + ReLU: h = relu(A @ xw1 + b1) ----------------
__global__ __launch_bounds__(256) void k_spmm1(const float* __restrict__ xw1,
                                               const int* __restrict__ row_start,
                                               const int* __restrict__ csr_col,
                                               const float* __restrict__ csr_val,
                                               const float* __restrict__ b1,
                                               float* __restrict__ h) {
    const int wid = (blockIdx.x * 256 + threadIdx.x) >> 6;   // one wave per node
    const int lane = threadIdx.x & 63;
    if (wid >= NN) return;
    const int s = row_start[wid], e = row_start[wid + 1];
    float2 acc = make_float2(0.f, 0.f);
    for (int base = s; base < e; base += 64) {
        const int n = min(64, e - base);
        int c = 0; float v = 0.f;
        if (lane < n) { c = csr_col[base + lane]; v = csr_val[base + lane]; }
        int j = 0;
        for (; j + 2 <= n; j += 2) {
            const int c0 = __shfl(c, j), c1 = __shfl(c, j + 1);
            const float v0 = __shfl(v, j), v1 = __shfl(v, j + 1);
            const float2 a0 = *(const float2*)(xw1 + c0 * 128 + (lane << 1));
            const float2 a1 = *(const float2*)(xw1 + c1 * 128 + (lane << 1));
            acc.x = fmaf(v0, a0.x, acc.x);
            acc.y = fmaf(v0, a0.y, acc.y);
            acc.x = fmaf(v1, a1.x, acc.x);
            acc.y = fmaf(v1, a1.y, acc.y);
        }
        if (j < n) {
            const int c0 = __shfl(c, j);
            const float v0 = __shfl(v, j);
            const float2 a0 = *(const float2*)(xw1 + c0 * 128 + (lane << 1));
            acc.x = fmaf(v0, a0.x, acc.x);
            acc.y = fmaf(v0, a0.y, acc.y);
        }
    }
    const float2 bb = *(const float2*)(b1 + (lane << 1));
    acc.x = fmaxf(acc.x + bb.x, 0.f);
    acc.y = fmaxf(acc.y + bb.y, 0.f);
    *(float2*)(h + wid * 128 + (lane << 1)) = acc;
}

// ---------------- GEMM2: hw4 = h @ W4  [NN,128]x[128,16] ----------------
__global__ __launch_bounds__(256) void k_gemm2(const float* __restrict__ h,
                                               const float* __restrict__ W4,
                                               float* __restrict__ y) {
    __shared__ float w4s[128 * 16];
    __shared__ float hs[16 * 132];   // padded: (4r + k) % 32 distinct per wave
    const int t = threadIdx.x;
    for (int i = t; i < 128 * 16; i += 256) w4s[i] = W4[i];
    const int row0 = blockIdx.x * 16;
    for (int idx4 = t; idx4 < 512; idx4 += 256) {   // 512 float4s = 16 rows
        const int r = idx4 >> 5;
        const int c4 = (idx4 & 31) * 4;
        const int row = row0 + r;
        float4 v = (row < NN) ? *(const float4*)(h + row * 128 + c4)
                              : make_float4(0.f, 0.f, 0.f, 0.f);
        *(float4*)(&hs[r * 132 + c4]) = v;
    }
    __syncthreads();
    const int r = t >> 4, c = t & 15;
    float acc = 0.f;
#pragma unroll
    for (int k = 0; k < 128; ++k) acc = fmaf(hs[r * 132 + k], w4s[k * 16 + c], acc);
    const int row = row0 + r;
    if (row < NN) y[row * 16 + c] = acc;
}

// ---------------- SpMM2 + bias + log_softmax ----------------
__global__ __launch_bounds__(256) void k_spmm2(const float* __restrict__ hw4,
                                               const int* __restrict__ row_start,
                                               const int* __restrict__ csr_col,
                                               const float* __restrict__ csr_val,
                                               const float* __restrict__ b4,
                                               float* __restrict__ out) {
    const int wid = (blockIdx.x * 256 + threadIdx.x) >> 6;   // one wave per node
    const int lane = threadIdx.x & 63;
    if (wid >= NN) return;
    const int f = lane & 15, g = lane >> 4;   // 4 edges in parallel
    const int s = row_start[wid], e = row_start[wid + 1];
    float acc = 0.f;
    for (int base = s + g; base < e; base += 4) {
        const int c = csr_col[base];
        const float v = csr_val[base];
        acc = fmaf(v, hw4[c * 16 + f], acc);
    }
    acc += __shfl_xor(acc, 16);
    acc += __shfl_xor(acc, 32);
    acc += b4[f];
    float m = acc;
#pragma unroll
    for (int off = 1; off < 16; off <<= 1) m = fmaxf(m, __shfl_xor(m, off));
    const float ex = __expf(acc - m);
    float sum = ex;
#pragma unroll
    for (int off = 1; off < 16; off <<= 1) sum += __shfl_xor(sum, off);
    const float res = acc - m - __logf(sum);
    if (lane < 16) out[wid * 16 + f] = res;
}

extern "C" void kernel_launch(void* const* d_in, const int* in_sizes, int n_in,
                              void* d_out, int out_size, void* d_ws, size_t ws_size,
                              hipStream_t stream) {
    const float* x        = (const float*)d_in[0];
    const float* edge_val = (const float*)d_in[1];
    const float* W1       = (const float*)d_in[2];
    const float* b1       = (const float*)d_in[3];
    const float* W4       = (const float*)d_in[4];
    const float* b4       = (const float*)d_in[5];
    const int*   edge_row = (const int*)d_in[6];
    const int*   edge_col = (const int*)d_in[7];
    float* out = (float*)d_out;

    char* ws = (char*)d_ws;
    size_t off = 0;
    auto alloc = [&](size_t bytes) -> void* {
        void* p = ws + off;
        off = (off + bytes + 255) & ~(size_t)255;
        return p;
    };
    float* xw1      = (float*)alloc((size_t)NN * 128 * 4);  // 51.2 MB (reused as hw4)
    float* h        = (float*)alloc((size_t)NN * 128 * 4);  // 51.2 MB
    int*   cnt      = (int*)alloc((size_t)NN * 4);
    int*   row_start= (int*)alloc((size_t)(NN + 1) * 4);
    int*   cursor   = (int*)alloc((size_t)NN * 4);
    int*   bsum     = (int*)alloc((size_t)NB * 4);
    int*   csr_col  = (int*)alloc((size_t)NE * 4);          // 12.8 MB
    float* csr_val  = (float*)alloc((size_t)NE * 4);        // 12.8 MB
    float* hw4 = xw1;  // xw1 dead after k_spmm1

    hipMemsetAsync(cnt, 0, (size_t)NN * 4, stream);

    k_gemm1<<<NN / 32, 256, 0, stream>>>(x, W1, xw1);
    k_hist<<<(NE + 255) / 256, 256, 0, stream>>>(edge_row, cnt);
    k_scanA<<<NB, 256, 0, stream>>>(cnt, bsum);
    k_scanB<<<1, 256, 0, stream>>>(bsum);
    k_scanC<<<NB, 256, 0, stream>>>(cnt, bsum, row_start, cursor);
    k_scatter<<<(NE + 255) / 256, 256, 0, stream>>>(edge_row, edge_col, edge_val,
                                                    cursor, csr_col, csr_val);
    k_spmm1<<<(NN + 3) / 4, 256, 0, stream>>>(xw1, row_start, csr_col, csr_val, b1, h);
    k_gemm2<<<(NN + 15) / 16, 256, 0, stream>>>(h, W4, hw4);
    k_spmm2<<<(NN + 3) / 4, 256, 0, stream>>>(hw4, row_start, csr_col, csr_val, b4, out);
}

// Round 3
// 746.947 us; speedup vs baseline: 1.1665x; 1.1665x over previous
//
#include <hip/hip_runtime.h>
#include <hip/hip_bf16.h>

// Problem constants (fixed by reference)
constexpr int NN = 100000;   // nodes
constexpr int NE = 3200000;  // edges
constexpr int SCAN_CHUNK = 512;
constexpr int NB = (NN + SCAN_CHUNK - 1) / SCAN_CHUNK;  // 196 scan blocks

__device__ __forceinline__ unsigned short f2bf(float f) {
    unsigned int u = __float_as_uint(f);
    unsigned int r = (u + 0x7fffu + ((u >> 16) & 1u)) >> 16;   // RNE
    return (unsigned short)r;
}

// ---------------- GEMM1: xw1 = bf16(x @ W1)  [NN,128]x[128,128] ----------------
__global__ __launch_bounds__(256) void k_gemm1(const float* __restrict__ x,
                                               const float* __restrict__ W,
                                               unsigned short* __restrict__ y) {
    __shared__ float ws_[128 * 128];   // 64 KB: whole W1
    __shared__ float xs[8][128];       // 8 staged rows
    const int t = threadIdx.x;
    for (int i = t; i < 128 * 128; i += 256) ws_[i] = W[i];

    const int rowg = t >> 5;          // 0..7 (row within sub-tile)
    const int cq   = (t & 31) * 4;    // 4 output cols
    const int row0 = blockIdx.x * 32;

    for (int rs = 0; rs < 32; rs += 8) {
        __syncthreads();
        {   // stage 8 rows (1024 floats) as 256 float4s
            const int r  = t >> 5;
            const int c4 = (t & 31) * 4;
            const int row = row0 + rs + r;
            float4 val = (row < NN) ? *(const float4*)(x + row * 128 + c4)
                                    : make_float4(0.f, 0.f, 0.f, 0.f);
            *(float4*)(&xs[r][c4]) = val;
        }
        __syncthreads();
        float4 acc = make_float4(0.f, 0.f, 0.f, 0.f);
#pragma unroll
        for (int k = 0; k < 128; ++k) {
            const float xv = xs[rowg][k];
            const float4 wv = *(const float4*)(&ws_[k * 128 + cq]);
            acc.x = fmaf(xv, wv.x, acc.x);
            acc.y = fmaf(xv, wv.y, acc.y);
            acc.z = fmaf(xv, wv.z, acc.z);
            acc.w = fmaf(xv, wv.w, acc.w);
        }
        const int row = row0 + rs + rowg;
        if (row < NN) {
            ushort4 o;
            o.x = f2bf(acc.x); o.y = f2bf(acc.y);
            o.z = f2bf(acc.z); o.w = f2bf(acc.w);
            *(ushort4*)(y + row * 128 + cq) = o;   // 8B store
        }
    }
}

// ---------------- CSR build ----------------
__global__ __launch_bounds__(256) void k_hist(const int* __restrict__ row, int* __restrict__ cnt) {
    int i = blockIdx.x * 256 + threadIdx.x;
    if (i < NE) atomicAdd(&cnt[row[i]], 1);
}

__global__ __launch_bounds__(256) void k_scanA(const int* __restrict__ cnt, int* __restrict__ bsum) {
    __shared__ int sd[256];
    const int t = threadIdx.x;
    const int i0 = blockIdx.x * SCAN_CHUNK + t * 2;
    int s = 0;
    if (i0 < NN) s += cnt[i0];
    if (i0 + 1 < NN) s += cnt[i0 + 1];
    sd[t] = s;
    __syncthreads();
    for (int off = 128; off > 0; off >>= 1) {
        if (t < off) sd[t] += sd[t + off];
        __syncthreads();
    }
    if (t == 0) bsum[blockIdx.x] = sd[0];
}

__global__ __launch_bounds__(256) void k_scanB(int* __restrict__ bsum) {
    __shared__ int sd[256];
    const int t = threadIdx.x;
    const int v = (t < NB) ? bsum[t] : 0;
    sd[t] = v;
    __syncthreads();
    for (int off = 1; off < 256; off <<= 1) {
        int a = sd[t];
        int b = (t >= off) ? sd[t - off] : 0;
        __syncthreads();
        sd[t] = a + b;
        __syncthreads();
    }
    if (t < NB) bsum[t] = sd[t] - v;  // exclusive
}

__global__ __launch_bounds__(256) void k_scanC(const int* __restrict__ cnt,
                                               const int* __restrict__ bsum,
                                               int* __restrict__ row_start,
                                               int* __restrict__ cursor) {
    __shared__ int sd[256];
    const int t = threadIdx.x;
    const int i0 = blockIdx.x * SCAN_CHUNK + t * 2;
    const int c0 = (i0 < NN) ? cnt[i0] : 0;
    const int c1 = (i0 + 1 < NN) ? cnt[i0 + 1] : 0;
    const int s = c0 + c1;
    sd[t] = s;
    __syncthreads();
    for (int off = 1; off < 256; off <<= 1) {
        int a = sd[t];
        int b = (t >= off) ? sd[t - off] : 0;
        __syncthreads();
        sd[t] = a + b;
        __syncthreads();
    }
    const int excl = sd[t] - s + bsum[blockIdx.x];
    if (i0 < NN)     { row_start[i0] = excl;          cursor[i0] = excl; }
    if (i0 + 1 < NN) { row_start[i0 + 1] = excl + c0; cursor[i0 + 1] = excl + c0; }
    if (blockIdx.x == 0 && t == 0) row_start[NN] = NE;
}

// packed CSR record: .x = col, .y = val bits  (single 8B store per edge)
__global__ __launch_bounds__(256) void k_scatter(const int* __restrict__ erow,
                                                 const int* __restrict__ ecol,
                                                 const float* __restrict__ eval_,
                                                 int* __restrict__ cursor,
                                                 uint2* __restrict__ recs) {
    int i = blockIdx.x * 256 + threadIdx.x;
    if (i < NE) {
        int r = erow[i];
        int p = atomicAdd(&cursor[r], 1);
        uint2 rec;
        rec.x = (unsigned int)ecol[i];
        rec.y = __float_as_uint(eval_[i]);
        recs[p] = rec;
    }
}

// ---------------- SpMM1 + bias + ReLU: h = relu(A @ xw1 + b1) ----------------
// xw1 is bf16 [NN,128]: row = 64 uints (2 feats each). Lane handles feats 2*lane, 2*lane+1.
__global__ __launch_bounds__(256) void k_spmm1(const unsigned int* __restrict__ xw1u,
                                               const int* __restrict__ row_start,
                                               const uint2* __restrict__ recs,
                                               const float* __restrict__ b1,
                                               float* __restrict__ h) {
    const int wid = (blockIdx.x * 256 + threadIdx.x) >> 6;   // one wave per node
    const int lane = threadIdx.x & 63;
    if (wid >= NN) return;
    const int s = row_start[wid], e = row_start[wid + 1];
    float2 acc = make_float2(0.f, 0.f);
    for (int base = s; base < e; base += 64) {
        const int n = min(64, e - base);
        uint2 rv = make_uint2(0u, 0u);
        if (lane < n) rv = recs[base + lane];
        int j = 0;
        for (; j + 2 <= n; j += 2) {
            const int c0 = __shfl((int)rv.x, j), c1 = __shfl((int)rv.x, j + 1);
            const float v0 = __uint_as_float((unsigned int)__shfl((int)rv.y, j));
            const float v1 = __uint_as_float((unsigned int)__shfl((int)rv.y, j + 1));
            const unsigned int u0 = xw1u[c0 * 64 + lane];
            const unsigned int u1 = xw1u[c1 * 64 + lane];
            const float a0x = __uint_as_float(u0 << 16);
            const float a0y = __uint_as_float(u0 & 0xffff0000u);
            const float a1x = __uint_as_float(u1 << 16);
            const float a1y = __uint_as_float(u1 & 0xffff0000u);
            acc.x = fmaf(v0, a0x, acc.x);
            acc.y = fmaf(v0, a0y, acc.y);
            acc.x = fmaf(v1, a1x, acc.x);
            acc.y = fmaf(v1, a1y, acc.y);
        }
        if (j < n) {
            const int c0 = __shfl((int)rv.x, j);
            const float v0 = __uint_as_float((unsigned int)__shfl((int)rv.y, j));
            const unsigned int u0 = xw1u[c0 * 64 + lane];
            acc.x = fmaf(v0, __uint_as_float(u0 << 16), acc.x);
            acc.y = fmaf(v0, __uint_as_float(u0 & 0xffff0000u), acc.y);
        }
    }
    const float2 bb = *(const float2*)(b1 + (lane << 1));
    acc.x = fmaxf(acc.x + bb.x, 0.f);
    acc.y = fmaxf(acc.y + bb.y, 0.f);
    *(float2*)(h + wid * 128 + (lane << 1)) = acc;
}

// ---------------- GEMM2: hw4 = bf16(h @ W4)  [NN,128]x[128,16] ----------------
__global__ __launch_bounds__(256) void k_gemm2(const float* __restrict__ h,
                                               const float* __restrict__ W4,
                                               unsigned short* __restrict__ y) {
    __shared__ float w4s[128 * 16];
    __shared__ float hs[16 * 132];   // padded
    const int t = threadIdx.x;
    for (int i = t; i < 128 * 16; i += 256) w4s[i] = W4[i];
    const int row0 = blockIdx.x * 16;
    for (int idx4 = t; idx4 < 512; idx4 += 256) {   // 512 float4s = 16 rows
        const int r = idx4 >> 5;
        const int c4 = (idx4 & 31) * 4;
        const int row = row0 + r;
        float4 v = (row < NN) ? *(const float4*)(h + row * 128 + c4)
                              : make_float4(0.f, 0.f, 0.f, 0.f);
        *(float4*)(&hs[r * 132 + c4]) = v;
    }
    __syncthreads();
    const int r = t >> 4, c = t & 15;
    float acc = 0.f;
#pragma unroll
    for (int k = 0; k < 128; ++k) acc = fmaf(hs[r * 132 + k], w4s[k * 16 + c], acc);
    const int row = row0 + r;
    if (row < NN) y[row * 16 + c] = f2bf(acc);
}

// ---------------- SpMM2 + bias + log_softmax ----------------
// hw4 is bf16 [NN,16] = 32B rows (L2-resident: 3.2 MB total)
__global__ __launch_bounds__(256) void k_spmm2(const __hip_bfloat16* __restrict__ hw4,
                                               const int* __restrict__ row_start,
                                               const uint2* __restrict__ recs,
                                               const float* __restrict__ b4,
                                               float* __restrict__ out) {
    const int wid = (blockIdx.x * 256 + threadIdx.x) >> 6;   // one wave per node
    const int lane = threadIdx.x & 63;
    if (wid >= NN) return;
    const int f = lane & 15, g = lane >> 4;   // 4 edges in parallel
    const int s = row_start[wid], e = row_start[wid + 1];
    float acc = 0.f;
    for (int base = s + g; base < e; base += 4) {
        const uint2 rv = recs[base];
        const int c = (int)rv.x;
        const float v = __uint_as_float(rv.y);
        const float a = __uint_as_float(((unsigned int)*(const unsigned short*)(hw4 + c * 16 + f)) << 16);
        acc = fmaf(v, a, acc);
    }
    acc += __shfl_xor(acc, 16);
    acc += __shfl_xor(acc, 32);
    acc += b4[f];
    float m = acc;
#pragma unroll
    for (int off = 1; off < 16; off <<= 1) m = fmaxf(m, __shfl_xor(m, off));
    const float ex = __expf(acc - m);
    float sum = ex;
#pragma unroll
    for (int off = 1; off < 16; off <<= 1) sum += __shfl_xor(sum, off);
    const float res = acc - m - __logf(sum);
    if (lane < 16) out[wid * 16 + f] = res;
}

extern "C" void kernel_launch(void* const* d_in, const int* in_sizes, int n_in,
                              void* d_out, int out_size, void* d_ws, size_t ws_size,
                              hipStream_t stream) {
    const float* x        = (const float*)d_in[0];
    const float* edge_val = (const float*)d_in[1];
    const float* W1       = (const float*)d_in[2];
    const float* b1       = (const float*)d_in[3];
    const float* W4       = (const float*)d_in[4];
    const float* b4       = (const float*)d_in[5];
    const int*   edge_row = (const int*)d_in[6];
    const int*   edge_col = (const int*)d_in[7];
    float* out = (float*)d_out;

    char* ws = (char*)d_ws;
    size_t off = 0;
    auto alloc = [&](size_t bytes) -> void* {
        void* p = ws + off;
        off = (off + bytes + 255) & ~(size_t)255;
        return p;
    };
    unsigned short* xw1 = (unsigned short*)alloc((size_t)NN * 128 * 2);  // 25.6 MB bf16
    float* h            = (float*)alloc((size_t)NN * 128 * 4);           // 51.2 MB
    unsigned short* hw4 = (unsigned short*)alloc((size_t)NN * 16 * 2);   // 3.2 MB bf16
    int*   cnt          = (int*)alloc((size_t)NN * 4);
    int*   row_start    = (int*)alloc((size_t)(NN + 1) * 4);
    int*   cursor       = (int*)alloc((size_t)NN * 4);
    int*   bsum         = (int*)alloc((size_t)NB * 4);
    uint2* recs         = (uint2*)alloc((size_t)NE * 8);                 // 25.6 MB

    hipMemsetAsync(cnt, 0, (size_t)NN * 4, stream);

    k_gemm1<<<NN / 32, 256, 0, stream>>>(x, W1, xw1);
    k_hist<<<(NE + 255) / 256, 256, 0, stream>>>(edge_row, cnt);
    k_scanA<<<NB, 256, 0, stream>>>(cnt, bsum);
    k_scanB<<<1, 256, 0, stream>>>(bsum);
    k_scanC<<<NB, 256, 0, stream>>>(cnt, bsum, row_start, cursor);
    k_scatter<<<(NE + 255) / 256, 256, 0, stream>>>(edge_row, edge_col, edge_val,
                                                    cursor, recs);
    k_spmm1<<<(NN + 3) / 4, 256, 0, stream>>>((const unsigned int*)xw1, row_start, recs, b1, h);
    k_gemm2<<<(NN + 15) / 16, 256, 0, stream>>>(h, W4, hw4);
    k_spmm2<<<(NN + 3) / 4, 256, 0, stream>>>((const __hip_bfloat16*)hw4, row_start, recs, b4, out);
}